// Round 1
// baseline (681.943 us; speedup 1.0000x reference)
//
#include <hip/hip_runtime.h>

typedef __attribute__((ext_vector_type(8))) short s16x8;
typedef __attribute__((ext_vector_type(4))) short s16x4;
typedef __attribute__((ext_vector_type(4))) float f32x4;
typedef unsigned short u16;

__device__ __forceinline__ u16 f2bf(float f) {
  unsigned u = __builtin_bit_cast(unsigned, f);
  return (u16)((u + 0x7fffu + ((u >> 16) & 1u)) >> 16);  // RNE fp32->bf16
}

// ---------------------------------------------------------------------------
// GEMM: Y[m,n] = sum_k A[m,k] * W[n,k]   (i.e. A @ W^T; W row-major [N][K])
// A_IS_F32: A is fp32 (x), convert to bf16 during staging; else A is bf16.
// OUT_QKV : write bf16 into [b,h,s,dh] layout (z selects Q/K/V); else fp32
//           row-major [M][N] (final output projection -> d_out).
// Block 256 = 4 waves; tile 128x128, BK=32; per-wave 64x64 = 4x4 MFMA tiles.
// LDS row stride 40 elems (80 B = 20 words): frag reads are 2-way max (free).
// ---------------------------------------------------------------------------
#define LDT 40

template<bool A_IS_F32, bool OUT_QKV>
__global__ __launch_bounds__(256)
void gemm_bt(const void* __restrict__ Ap,
             const float* __restrict__ W0, const float* __restrict__ W1,
             const float* __restrict__ W2,
             u16* __restrict__ o0, u16* __restrict__ o1, u16* __restrict__ o2,
             float* __restrict__ oF)
{
  const int bx = blockIdx.x;   // n-tile
  const int by = blockIdx.y;   // m-tile
  const int bz = blockIdx.z;   // which projection (QKV fused launch)
  const float* W = (bz == 0) ? W0 : ((bz == 1) ? W1 : W2);
  u16* oQ = (bz == 0) ? o0 : ((bz == 1) ? o1 : o2);

  __shared__ u16 As[128 * LDT];
  __shared__ u16 Bs[128 * LDT];

  const int tid  = threadIdx.x;
  const int w    = tid >> 6;
  const int lane = tid & 63;
  const int quad = lane >> 4;
  const int l15  = lane & 15;
  const int wm   = (w >> 1) * 64;
  const int wn   = (w & 1) * 64;

  f32x4 acc[4][4];
  #pragma unroll
  for (int i = 0; i < 4; ++i)
    #pragma unroll
    for (int j = 0; j < 4; ++j)
      acc[i][j] = (f32x4){0.f, 0.f, 0.f, 0.f};

  for (int k0 = 0; k0 < 1024; k0 += 32) {
    // ---- stage A tile (128 x 32) ----
    if (A_IS_F32) {
      const float* A = (const float*)Ap;
      const int col = (tid & 7) * 4;
      #pragma unroll
      for (int p = 0; p < 4; ++p) {
        const int row = (tid >> 3) + p * 32;
        f32x4 v = *(const f32x4*)(A + (size_t)(by * 128 + row) * 1024 + k0 + col);
        s16x4 pk;
        pk[0] = (short)f2bf(v[0]); pk[1] = (short)f2bf(v[1]);
        pk[2] = (short)f2bf(v[2]); pk[3] = (short)f2bf(v[3]);
        *(s16x4*)&As[row * LDT + col] = pk;
      }
    } else {
      const u16* A = (const u16*)Ap;
      const int col = (tid & 3) * 8;
      #pragma unroll
      for (int p = 0; p < 2; ++p) {
        const int row = (tid >> 2) + p * 64;
        *(s16x8*)&As[row * LDT + col] =
            *(const s16x8*)(A + (size_t)(by * 128 + row) * 1024 + k0 + col);
      }
    }
    // ---- stage B tile (W rows 128 x 32, fp32 -> bf16) ----
    {
      const int col = (tid & 7) * 4;
      #pragma unroll
      for (int p = 0; p < 4; ++p) {
        const int row = (tid >> 3) + p * 32;
        f32x4 v = *(const f32x4*)(W + (size_t)(bx * 128 + row) * 1024 + k0 + col);
        s16x4 pk;
        pk[0] = (short)f2bf(v[0]); pk[1] = (short)f2bf(v[1]);
        pk[2] = (short)f2bf(v[2]); pk[3] = (short)f2bf(v[3]);
        *(s16x4*)&Bs[row * LDT + col] = pk;
      }
    }
    __syncthreads();

    s16x8 af[4], bf[4];
    #pragma unroll
    for (int i = 0; i < 4; ++i)
      af[i] = *(const s16x8*)&As[(wm + i * 16 + l15) * LDT + quad * 8];
    #pragma unroll
    for (int i = 0; i < 4; ++i)
      bf[i] = *(const s16x8*)&Bs[(wn + i * 16 + l15) * LDT + quad * 8];
    #pragma unroll
    for (int mt = 0; mt < 4; ++mt)
      #pragma unroll
      for (int nt = 0; nt < 4; ++nt)
        acc[mt][nt] = __builtin_amdgcn_mfma_f32_16x16x32_bf16(
            af[mt], bf[nt], acc[mt][nt], 0, 0, 0);
    __syncthreads();
  }

  // ---- epilogue: C/D layout is col = lane&15, row = quad*4 + reg ----
  #pragma unroll
  for (int mt = 0; mt < 4; ++mt)
    #pragma unroll
    for (int nt = 0; nt < 4; ++nt)
      #pragma unroll
      for (int r = 0; r < 4; ++r) {
        const int row = by * 128 + wm + mt * 16 + quad * 4 + r;  // token m
        const int col = bx * 128 + wn + nt * 16 + l15;           // feature n
        const float v = acc[mt][nt][r];
        if (OUT_QKV) {
          const int b = row >> 11, s = row & 2047, hh = col >> 6, d = col & 63;
          oQ[(size_t)(b * 16 + hh) * 131072 + s * 64 + d] = f2bf(v);
        } else {
          oF[(size_t)row * 1024 + col] = v;
        }
      }
}

// ---------------------------------------------------------------------------
// Flash attention (causal), one block = 128 queries for one (b,h).
// Q/K/V bf16 in [bh][s][64]. 4 waves x 32 q-rows. K-tiles of 64 keys.
// S = Q K^T via mfma 16x16x32 (A: Q rows contiguous; B: K rows contiguous,
// since B[k][n] = K[n][k] wants 8 contiguous dh elems of K row n).
// Online softmax in C/D layout; P -> per-wave LDS -> A-operand layout;
// V staged transposed so PV B-frag is contiguous ds_read_b128.
// ---------------------------------------------------------------------------
__global__ __launch_bounds__(256)
void attn_kernel(const u16* __restrict__ Qg, const u16* __restrict__ Kg,
                 const u16* __restrict__ Vg, u16* __restrict__ out)
{
  const int qt = blockIdx.x;     // query tile (16)
  const int bh = blockIdx.y;     // (64)
  const int b = bh >> 4, h = bh & 15;

  __shared__ u16 Qs[128 * 72];
  __shared__ u16 Ks[64 * 72];
  __shared__ u16 Vt[64 * 72];        // Vt[dh][seq]
  __shared__ u16 Ps[4][32 * 72];     // per-wave P scratch

  const int tid = threadIdx.x;
  const int w = tid >> 6, lane = tid & 63, quad = lane >> 4, l15 = lane & 15;
  const size_t base = (size_t)bh * 131072;

  // stage Q tile (128 x 64)
  {
    const int col = (tid & 7) * 8;
    #pragma unroll
    for (int p = 0; p < 4; ++p) {
      const int row = (tid >> 3) + p * 32;
      *(s16x8*)&Qs[row * 72 + col] =
          *(const s16x8*)(Qg + base + (size_t)(qt * 128 + row) * 64 + col);
    }
  }
  __syncthreads();

  // Q A-frags: A[m=lane&15][k=quad*8+j], wave w owns rows w*32..w*32+31
  s16x8 aq[2][2];
  #pragma unroll
  for (int mt = 0; mt < 2; ++mt)
    #pragma unroll
    for (int ks = 0; ks < 2; ++ks)
      aq[mt][ks] = *(const s16x8*)&Qs[(w * 32 + mt * 16 + l15) * 72 + ks * 32 + quad * 8];

  f32x4 O[2][4];
  float mi[2][4], li[2][4];
  #pragma unroll
  for (int mt = 0; mt < 2; ++mt) {
    #pragma unroll
    for (int dt = 0; dt < 4; ++dt) O[mt][dt] = (f32x4){0.f, 0.f, 0.f, 0.f};
    #pragma unroll
    for (int r = 0; r < 4; ++r) { mi[mt][r] = -1e30f; li[mt][r] = 0.f; }
  }

  const int kend = 2 * qt + 2;  // causal: keys < (qt+1)*128
  for (int j = 0; j < kend; ++j) {
    __syncthreads();
    // stage K tile (64 x 64)
    {
      const int col = (tid & 7) * 8;
      #pragma unroll
      for (int p = 0; p < 2; ++p) {
        const int row = (tid >> 3) + p * 32;
        *(s16x8*)&Ks[row * 72 + col] =
            *(const s16x8*)(Kg + base + (size_t)(j * 64 + row) * 64 + col);
      }
    }
    // stage V transposed
    for (int idx = tid; idx < 4096; idx += 256) {
      const int sr = idx >> 6, d = idx & 63;
      Vt[d * 72 + sr] = Vg[base + (size_t)(j * 64 + sr) * 64 + d];
    }
    __syncthreads();

    s16x8 bk[4][2];
    #pragma unroll
    for (int nt = 0; nt < 4; ++nt)
      #pragma unroll
      for (int ks = 0; ks < 2; ++ks)
        bk[nt][ks] = *(const s16x8*)&Ks[(nt * 16 + l15) * 72 + ks * 32 + quad * 8];

    // S = Q K^T * scale
    f32x4 S[2][4];
    #pragma unroll
    for (int mt = 0; mt < 2; ++mt)
      #pragma unroll
      for (int nt = 0; nt < 4; ++nt) {
        f32x4 z = (f32x4){0.f, 0.f, 0.f, 0.f};
        z = __builtin_amdgcn_mfma_f32_16x16x32_bf16(aq[mt][0], bk[nt][0], z, 0, 0, 0);
        z = __builtin_amdgcn_mfma_f32_16x16x32_bf16(aq[mt][1], bk[nt][1], z, 0, 0, 0);
        S[mt][nt] = z * 0.125f;  // 1/sqrt(64)
      }

    // causal mask (only the two diagonal-straddling tiles need it)
    if (j >= 2 * qt) {
      #pragma unroll
      for (int mt = 0; mt < 2; ++mt)
        #pragma unroll
        for (int nt = 0; nt < 4; ++nt)
          #pragma unroll
          for (int r = 0; r < 4; ++r) {
            const int kg = j * 64 + nt * 16 + l15;
            const int qg = qt * 128 + w * 32 + mt * 16 + quad * 4 + r;
            if (kg > qg) S[mt][nt][r] = -1e30f;
          }
    }

    // online softmax per q-row; rows live in lanes sharing quad (16 lanes)
    u16* Pw = Ps[w];
    #pragma unroll
    for (int mt = 0; mt < 2; ++mt)
      #pragma unroll
      for (int r = 0; r < 4; ++r) {
        const float s0 = S[mt][0][r], s1 = S[mt][1][r];
        const float s2 = S[mt][2][r], s3 = S[mt][3][r];
        float rm = fmaxf(fmaxf(s0, s1), fmaxf(s2, s3));
        #pragma unroll
        for (int off = 1; off < 16; off <<= 1)
          rm = fmaxf(rm, __shfl_xor(rm, off, 64));
        const float mold = mi[mt][r];
        const float mnew = fmaxf(mold, rm);
        const float alpha = __expf(mold - mnew);
        const float p0 = __expf(s0 - mnew), p1 = __expf(s1 - mnew);
        const float p2 = __expf(s2 - mnew), p3 = __expf(s3 - mnew);
        float rs = (p0 + p1) + (p2 + p3);
        #pragma unroll
        for (int off = 1; off < 16; off <<= 1)
          rs += __shfl_xor(rs, off, 64);
        li[mt][r] = li[mt][r] * alpha + rs;
        mi[mt][r] = mnew;
        #pragma unroll
        for (int dt = 0; dt < 4; ++dt) O[mt][dt][r] *= alpha;
        const int pr = (mt * 16 + quad * 4 + r) * 72 + l15;
        Pw[pr]      = f2bf(p0);
        Pw[pr + 16] = f2bf(p1);
        Pw[pr + 32] = f2bf(p2);
        Pw[pr + 48] = f2bf(p3);
      }

    // PV: A = P (32 x 64 keys), B = V (keys x dh) read via Vt transposed
    s16x8 ap[2][2], bv[4][2];
    #pragma unroll
    for (int mt = 0; mt < 2; ++mt)
      #pragma unroll
      for (int ks = 0; ks < 2; ++ks)
        ap[mt][ks] = *(const s16x8*)&Pw[(mt * 16 + l15) * 72 + ks * 32 + quad * 8];
    #pragma unroll
    for (int dt = 0; dt < 4; ++dt)
      #pragma unroll
      for (int ks = 0; ks < 2; ++ks)
        bv[dt][ks] = *(const s16x8*)&Vt[(dt * 16 + l15) * 72 + ks * 32 + quad * 8];
    #pragma unroll
    for (int mt = 0; mt < 2; ++mt)
      #pragma unroll
      for (int dt = 0; dt < 4; ++dt) {
        O[mt][dt] = __builtin_amdgcn_mfma_f32_16x16x32_bf16(ap[mt][0], bv[dt][0], O[mt][dt], 0, 0, 0);
        O[mt][dt] = __builtin_amdgcn_mfma_f32_16x16x32_bf16(ap[mt][1], bv[dt][1], O[mt][dt], 0, 0, 0);
      }
  }

  // epilogue: attn_out[b, s, h*64 + d] bf16 (A-matrix for the final GEMM)
  #pragma unroll
  for (int mt = 0; mt < 2; ++mt)
    #pragma unroll
    for (int dt = 0; dt < 4; ++dt)
      #pragma unroll
      for (int r = 0; r < 4; ++r) {
        const float v = O[mt][dt][r] / li[mt][r];
        const int sq = qt * 128 + w * 32 + mt * 16 + quad * 4 + r;
        out[(size_t)(b * 2048 + sq) * 1024 + h * 64 + dt * 16 + l15] = f2bf(v);
      }
}

extern "C" void kernel_launch(void* const* d_in, const int* in_sizes, int n_in,
                              void* d_out, int out_size, void* d_ws, size_t ws_size,
                              hipStream_t stream) {
  (void)in_sizes; (void)n_in; (void)out_size; (void)ws_size;
  const float* x  = (const float*)d_in[0];
  const float* Wq = (const float*)d_in[1];
  const float* Wk = (const float*)d_in[2];
  const float* Wv = (const float*)d_in[3];
  const float* Wo = (const float*)d_in[4];
  float* out = (float*)d_out;

  // workspace carve (bf16): Q,K,V in [b,h,s,dh]; AO in [b,s,d]. 64 MB total.
  u16* Qb = (u16*)d_ws;
  u16* Kb = Qb + 8388608;
  u16* Vb = Kb + 8388608;
  u16* AO = Vb + 8388608;

  dim3 blk(256);
  // Q,K,V projections fused over blockIdx.z
  gemm_bt<true,  true ><<<dim3(8, 64, 3), blk, 0, stream>>>(
      x, Wq, Wk, Wv, Qb, Kb, Vb, nullptr);
  // causal flash attention
  attn_kernel<<<dim3(16, 64), blk, 0, stream>>>(Qb, Kb, Vb, AO);
  // output projection -> fp32 d_out
  gemm_bt<false, false><<<dim3(8, 64, 1), blk, 0, stream>>>(
      AO, Wo, Wo, Wo, nullptr, nullptr, nullptr, out);
}

// Round 2
// 385.069 us; speedup vs baseline: 1.7710x; 1.7710x over previous
//
#include <hip/hip_runtime.h>

typedef __attribute__((ext_vector_type(8))) short s16x8;
typedef __attribute__((ext_vector_type(4))) short s16x4;
typedef __attribute__((ext_vector_type(4))) float f32x4;
typedef unsigned short u16;

__device__ __forceinline__ u16 f2bf(float f) {
  unsigned u = __builtin_bit_cast(unsigned, f);
  return (u16)((u + 0x7fffu + ((u >> 16) & 1u)) >> 16);  // RNE fp32->bf16
}

// 0.125 (1/sqrt(dh)) * log2(e): puts scores in log2 domain for v_exp_f32
#define QSCALE 0.18033688011112042f

// ---------------------------------------------------------------------------
// GEMM: Y[m,n] = sum_k A[m,k] * W[n,k]   (A @ W^T; W row-major [N][K])
// ---------------------------------------------------------------------------
#define LDT 40

template<bool A_IS_F32, bool OUT_QKV>
__global__ __launch_bounds__(256)
void gemm_bt(const void* __restrict__ Ap,
             const float* __restrict__ W0, const float* __restrict__ W1,
             const float* __restrict__ W2,
             u16* __restrict__ o0, u16* __restrict__ o1, u16* __restrict__ o2,
             float* __restrict__ oF)
{
  const int bx = blockIdx.x;
  const int by = blockIdx.y;
  const int bz = blockIdx.z;
  const float* W = (bz == 0) ? W0 : ((bz == 1) ? W1 : W2);
  u16* oQ = (bz == 0) ? o0 : ((bz == 1) ? o1 : o2);

  __shared__ u16 As[128 * LDT];
  __shared__ u16 Bs[128 * LDT];

  const int tid  = threadIdx.x;
  const int w    = tid >> 6;
  const int lane = tid & 63;
  const int quad = lane >> 4;
  const int l15  = lane & 15;
  const int wm   = (w >> 1) * 64;
  const int wn   = (w & 1) * 64;

  f32x4 acc[4][4];
  #pragma unroll
  for (int i = 0; i < 4; ++i)
    #pragma unroll
    for (int j = 0; j < 4; ++j)
      acc[i][j] = (f32x4){0.f, 0.f, 0.f, 0.f};

  for (int k0 = 0; k0 < 1024; k0 += 32) {
    if (A_IS_F32) {
      const float* A = (const float*)Ap;
      const int col = (tid & 7) * 4;
      #pragma unroll
      for (int p = 0; p < 4; ++p) {
        const int row = (tid >> 3) + p * 32;
        f32x4 v = *(const f32x4*)(A + (size_t)(by * 128 + row) * 1024 + k0 + col);
        s16x4 pk;
        pk[0] = (short)f2bf(v[0]); pk[1] = (short)f2bf(v[1]);
        pk[2] = (short)f2bf(v[2]); pk[3] = (short)f2bf(v[3]);
        *(s16x4*)&As[row * LDT + col] = pk;
      }
    } else {
      const u16* A = (const u16*)Ap;
      const int col = (tid & 3) * 8;
      #pragma unroll
      for (int p = 0; p < 2; ++p) {
        const int row = (tid >> 2) + p * 64;
        *(s16x8*)&As[row * LDT + col] =
            *(const s16x8*)(A + (size_t)(by * 128 + row) * 1024 + k0 + col);
      }
    }
    {
      const int col = (tid & 7) * 4;
      #pragma unroll
      for (int p = 0; p < 4; ++p) {
        const int row = (tid >> 3) + p * 32;
        f32x4 v = *(const f32x4*)(W + (size_t)(bx * 128 + row) * 1024 + k0 + col);
        s16x4 pk;
        pk[0] = (short)f2bf(v[0]); pk[1] = (short)f2bf(v[1]);
        pk[2] = (short)f2bf(v[2]); pk[3] = (short)f2bf(v[3]);
        *(s16x4*)&Bs[row * LDT + col] = pk;
      }
    }
    __syncthreads();

    s16x8 af[4], bf[4];
    #pragma unroll
    for (int i = 0; i < 4; ++i)
      af[i] = *(const s16x8*)&As[(wm + i * 16 + l15) * LDT + quad * 8];
    #pragma unroll
    for (int i = 0; i < 4; ++i)
      bf[i] = *(const s16x8*)&Bs[(wn + i * 16 + l15) * LDT + quad * 8];
    #pragma unroll
    for (int mt = 0; mt < 4; ++mt)
      #pragma unroll
      for (int nt = 0; nt < 4; ++nt)
        acc[mt][nt] = __builtin_amdgcn_mfma_f32_16x16x32_bf16(
            af[mt], bf[nt], acc[mt][nt], 0, 0, 0);
    __syncthreads();
  }

  #pragma unroll
  for (int mt = 0; mt < 4; ++mt)
    #pragma unroll
    for (int nt = 0; nt < 4; ++nt)
      #pragma unroll
      for (int r = 0; r < 4; ++r) {
        const int row = by * 128 + wm + mt * 16 + quad * 4 + r;
        const int col = bx * 128 + wn + nt * 16 + l15;
        float v = acc[mt][nt][r];
        if (OUT_QKV) {
          if (bz == 0) v *= QSCALE;  // fold softmax scale+log2e into Q
          const int b = row >> 11, s = row & 2047, hh = col >> 6, d = col & 63;
          oQ[(size_t)(b * 16 + hh) * 131072 + s * 64 + d] = f2bf(v);
        } else {
          oF[(size_t)row * 1024 + col] = v;
        }
      }
}

// ---------------------------------------------------------------------------
// V transpose: [bh][2048][64] -> [bh][64][2048] (bf16), one-shot, ~32MB.
// ---------------------------------------------------------------------------
__global__ __launch_bounds__(256)
void vtrans(const u16* __restrict__ Vb, u16* __restrict__ VT)
{
  const int st = blockIdx.x;   // 32 s-tiles of 64
  const int bh = blockIdx.y;   // 64
  __shared__ u16 T[64 * 72];
  const int tid = threadIdx.x;
  const size_t base = (size_t)bh * 131072;
  #pragma unroll
  for (int p = 0; p < 2; ++p) {
    const int idx = tid + p * 256;
    const int row = idx >> 3;          // s within tile
    const int col = (idx & 7) * 8;     // dh
    s16x8 v = *(const s16x8*)(Vb + base + (size_t)(st * 64 + row) * 64 + col);
    #pragma unroll
    for (int e = 0; e < 8; ++e) T[(col + e) * 72 + row] = v[e];
  }
  __syncthreads();
  #pragma unroll
  for (int p = 0; p < 2; ++p) {
    const int idx = tid + p * 256;
    const int drow = idx >> 3;         // dh
    const int scol = (idx & 7) * 8;    // s within tile
    *(s16x8*)(VT + base + (size_t)drow * 2048 + st * 64 + scol) =
        *(const s16x8*)&T[drow * 72 + scol];
  }
}

// ---------------------------------------------------------------------------
// Causal flash attention, statically balanced: block i owns q-tiles
// {31-i (waves 0,1), i (waves 2,3)}, 64 rows each. K-tiles of 64 keys.
// Q pre-scaled by 0.125*log2e -> exp2 softmax. K rows staged permuted
// (slot = (key&3)*16 + key>>2) so lane l15's 4 S columns are keys
// 4*l15..4*l15+3 -> P row-stores are single ds_write_b64.
// Row-sum l accumulated by MFMA vs all-ones B fragment (no sum shuffles).
// LDS 36KB -> 4 blocks/CU; all 1024 blocks resident.
// ---------------------------------------------------------------------------
__global__ __launch_bounds__(256, 4)
void attn_kernel(const u16* __restrict__ Qg, const u16* __restrict__ Kg,
                 const u16* __restrict__ VTg, u16* __restrict__ out)
{
  const int pi = blockIdx.x;           // 0..15 pair index
  const int bh = blockIdx.y;
  const int b = bh >> 4, h = bh & 15;
  const int qa = 31 - pi;              // heavy q-tile
  const int qb = pi;                   // light q-tile

  __shared__ u16 Qs[128 * 72];         // Q tiles; per-wave region reused as P
  __shared__ u16 Ks[64 * 72];          // permuted key rows
  __shared__ u16 Vt[64 * 72];          // Vt[dh][key]

  const int tid = threadIdx.x;
  const int w = tid >> 6, lane = tid & 63, quad = lane >> 4, l15 = lane & 15;
  const size_t base = (size_t)bh * 131072;

  // stage Q: Qs rows 0..63 = tile qa, 64..127 = tile qb
  {
    const int col = (tid & 7) * 8;
    #pragma unroll
    for (int p = 0; p < 4; ++p) {
      const int row = (tid >> 3) + p * 32;
      const int gq = (row < 64) ? (qa * 64 + row) : (qb * 64 + (row - 64));
      *(s16x8*)&Qs[row * 72 + col] =
          *(const s16x8*)(Qg + base + (size_t)gq * 64 + col);
    }
  }
  __syncthreads();

  const int myq  = (w < 2) ? qa : qb;  // wave's q-tile
  const int wrow = (w & 1) * 32;       // row base within tile
  const int qsb  = w * 32;             // wave's rows in Qs (== its P region)

  s16x8 aq[2][2];
  #pragma unroll
  for (int mt = 0; mt < 2; ++mt)
    #pragma unroll
    for (int ks = 0; ks < 2; ++ks)
      aq[mt][ks] = *(const s16x8*)&Qs[(qsb + mt * 16 + l15) * 72 + ks * 32 + quad * 8];

  u16* Pw = &Qs[qsb * 72];             // per-wave P scratch (own rows)

  s16x8 ones;
  #pragma unroll
  for (int e = 0; e < 8; ++e) ones[e] = (short)0x3F80;  // bf16 1.0

  f32x4 O[2][4], liacc[2];
  float mi[2][4];
  #pragma unroll
  for (int mt = 0; mt < 2; ++mt) {
    #pragma unroll
    for (int dt = 0; dt < 4; ++dt) O[mt][dt] = (f32x4){0.f, 0.f, 0.f, 0.f};
    liacc[mt] = (f32x4){0.f, 0.f, 0.f, 0.f};
    #pragma unroll
    for (int r = 0; r < 4; ++r) mi[mt][r] = -1e30f;
  }

  const int jmax = qa + 1;
  for (int j = 0; j < jmax; ++j) {
    // ---- stage K (permuted rows) and V^T, all waves ----
    #pragma unroll
    for (int p = 0; p < 2; ++p) {
      const int idx = tid + p * 256;
      const int key = idx >> 3, col = (idx & 7) * 8;
      const int slot = (key & 3) * 16 + (key >> 2);
      *(s16x8*)&Ks[slot * 72 + col] =
          *(const s16x8*)(Kg + base + (size_t)(j * 64 + key) * 64 + col);
    }
    #pragma unroll
    for (int p = 0; p < 2; ++p) {
      const int idx = tid + p * 256;
      const int d = idx >> 3, col = (idx & 7) * 8;
      *(s16x8*)&Vt[d * 72 + col] =
          *(const s16x8*)(VTg + base + (size_t)d * 2048 + j * 64 + col);
    }
    __syncthreads();

    if (j <= myq) {
      // ---- S = Q K^T (log2 domain; col of tile nt = key 4*l15+nt) ----
      f32x4 S[2][4];
      #pragma unroll
      for (int nt = 0; nt < 4; ++nt) {
        s16x8 b0 = *(const s16x8*)&Ks[(nt * 16 + l15) * 72 + quad * 8];
        s16x8 b1 = *(const s16x8*)&Ks[(nt * 16 + l15) * 72 + 32 + quad * 8];
        #pragma unroll
        for (int mt = 0; mt < 2; ++mt) {
          f32x4 z = (f32x4){0.f, 0.f, 0.f, 0.f};
          z = __builtin_amdgcn_mfma_f32_16x16x32_bf16(aq[mt][0], b0, z, 0, 0, 0);
          z = __builtin_amdgcn_mfma_f32_16x16x32_bf16(aq[mt][1], b1, z, 0, 0, 0);
          S[mt][nt] = z;
        }
      }
      if (j == myq) {  // diagonal tile: causal mask
        #pragma unroll
        for (int mt = 0; mt < 2; ++mt)
          #pragma unroll
          for (int nt = 0; nt < 4; ++nt)
            #pragma unroll
            for (int r = 0; r < 4; ++r) {
              const int kg = 4 * l15 + nt;
              const int qg = wrow + mt * 16 + quad * 4 + r;
              if (kg > qg) S[mt][nt][r] = -1e30f;
            }
      }
      // ---- online softmax; P packed as 4 consecutive keys per write ----
      #pragma unroll
      for (int mt = 0; mt < 2; ++mt)
        #pragma unroll
        for (int r = 0; r < 4; ++r) {
          float rm = fmaxf(fmaxf(S[mt][0][r], S[mt][1][r]),
                           fmaxf(S[mt][2][r], S[mt][3][r]));
          #pragma unroll
          for (int off = 1; off < 16; off <<= 1)
            rm = fmaxf(rm, __shfl_xor(rm, off, 64));
          const float mold = mi[mt][r];
          const float mnew = fmaxf(mold, rm);
          const float alpha = __builtin_amdgcn_exp2f(mold - mnew);
          mi[mt][r] = mnew;
          const float p0 = __builtin_amdgcn_exp2f(S[mt][0][r] - mnew);
          const float p1 = __builtin_amdgcn_exp2f(S[mt][1][r] - mnew);
          const float p2 = __builtin_amdgcn_exp2f(S[mt][2][r] - mnew);
          const float p3 = __builtin_amdgcn_exp2f(S[mt][3][r] - mnew);
          liacc[mt][r] *= alpha;
          #pragma unroll
          for (int dt = 0; dt < 4; ++dt) O[mt][dt][r] *= alpha;
          s16x4 pk;
          pk[0] = (short)f2bf(p0); pk[1] = (short)f2bf(p1);
          pk[2] = (short)f2bf(p2); pk[3] = (short)f2bf(p3);
          *(s16x4*)&Pw[(mt * 16 + quad * 4 + r) * 72 + 4 * l15] = pk;
        }
      // ---- PV + row-sum MFMA ----
      #pragma unroll
      for (int mt = 0; mt < 2; ++mt) {
        s16x8 a0 = *(const s16x8*)&Pw[(mt * 16 + l15) * 72 + quad * 8];
        s16x8 a1 = *(const s16x8*)&Pw[(mt * 16 + l15) * 72 + 32 + quad * 8];
        liacc[mt] = __builtin_amdgcn_mfma_f32_16x16x32_bf16(a0, ones, liacc[mt], 0, 0, 0);
        liacc[mt] = __builtin_amdgcn_mfma_f32_16x16x32_bf16(a1, ones, liacc[mt], 0, 0, 0);
        #pragma unroll
        for (int dt = 0; dt < 4; ++dt) {
          s16x8 b0 = *(const s16x8*)&Vt[(dt * 16 + l15) * 72 + quad * 8];
          s16x8 b1 = *(const s16x8*)&Vt[(dt * 16 + l15) * 72 + 32 + quad * 8];
          O[mt][dt] = __builtin_amdgcn_mfma_f32_16x16x32_bf16(a0, b0, O[mt][dt], 0, 0, 0);
          O[mt][dt] = __builtin_amdgcn_mfma_f32_16x16x32_bf16(a1, b1, O[mt][dt], 0, 0, 0);
        }
      }
    }
    __syncthreads();
  }

  // epilogue: out[b][s][h*64+d] bf16
  #pragma unroll
  for (int mt = 0; mt < 2; ++mt)
    #pragma unroll
    for (int r = 0; r < 4; ++r) {
      const float inv = __builtin_amdgcn_rcpf(liacc[mt][r]);
      const int sq = myq * 64 + wrow + mt * 16 + quad * 4 + r;
      #pragma unroll
      for (int dt = 0; dt < 4; ++dt)
        out[(size_t)(b * 2048 + sq) * 1024 + h * 64 + dt * 16 + l15] =
            f2bf(O[mt][dt][r] * inv);
    }
}

extern "C" void kernel_launch(void* const* d_in, const int* in_sizes, int n_in,
                              void* d_out, int out_size, void* d_ws, size_t ws_size,
                              hipStream_t stream) {
  (void)in_sizes; (void)n_in; (void)out_size; (void)ws_size;
  const float* x  = (const float*)d_in[0];
  const float* Wq = (const float*)d_in[1];
  const float* Wk = (const float*)d_in[2];
  const float* Wv = (const float*)d_in[3];
  const float* Wo = (const float*)d_in[4];
  float* out = (float*)d_out;

  // workspace (bf16): Q,K,V [b,h,s,dh]; VT [b,h,dh,s]; AO aliases dead V.
  u16* Qb = (u16*)d_ws;
  u16* Kb = Qb + 8388608;
  u16* Vb = Kb + 8388608;
  u16* VT = Vb + 8388608;
  u16* AO = Vb;  // V natural layout dead after vtrans

  dim3 blk(256);
  gemm_bt<true,  true ><<<dim3(8, 64, 3), blk, 0, stream>>>(
      x, Wq, Wk, Wv, Qb, Kb, Vb, nullptr);
  vtrans<<<dim3(32, 64), blk, 0, stream>>>(Vb, VT);
  attn_kernel<<<dim3(16, 64), blk, 0, stream>>>(Qb, Kb, VT, AO);
  gemm_bt<false, false><<<dim3(8, 64, 1), blk, 0, stream>>>(
      AO, Wo, Wo, Wo, nullptr, nullptr, nullptr, out);
}

// Round 3
// 334.301 us; speedup vs baseline: 2.0399x; 1.1519x over previous
//
#include <hip/hip_runtime.h>

typedef __attribute__((ext_vector_type(8))) short s16x8;
typedef __attribute__((ext_vector_type(4))) short s16x4;
typedef __attribute__((ext_vector_type(4))) float f32x4;
typedef unsigned short u16;

__device__ __forceinline__ u16 f2bf(float f) {
  unsigned u = __builtin_bit_cast(unsigned, f);
  return (u16)((u + 0x7fffu + ((u >> 16) & 1u)) >> 16);  // RNE fp32->bf16
}

// 0.125 (1/sqrt(dh)) * log2(e): scores in log2 domain for v_exp_f32
#define QSCALE 0.18033688011112042f

// async global->LDS, 16B per lane; LDS dst is wave-uniform base + lane*16
__device__ __forceinline__ void gld16(const u16* g, u16* l) {
  __builtin_amdgcn_global_load_lds(
      (const __attribute__((address_space(1))) void*)g,
      (__attribute__((address_space(3))) void*)l, 16, 0, 0);
}

// ---------------------------------------------------------------------------
// fp32 -> bf16 convert, 8 elems/thread
// ---------------------------------------------------------------------------
__global__ __launch_bounds__(256)
void cvt_bf16(const float* __restrict__ src, u16* __restrict__ dst, int n8)
{
  const int i = blockIdx.x * 256 + threadIdx.x;
  if (i < n8) {
    f32x4 a = ((const f32x4*)src)[2 * i];
    f32x4 b = ((const f32x4*)src)[2 * i + 1];
    s16x8 pk;
    pk[0] = (short)f2bf(a[0]); pk[1] = (short)f2bf(a[1]);
    pk[2] = (short)f2bf(a[2]); pk[3] = (short)f2bf(a[3]);
    pk[4] = (short)f2bf(b[0]); pk[5] = (short)f2bf(b[1]);
    pk[6] = (short)f2bf(b[2]); pk[7] = (short)f2bf(b[3]);
    ((s16x8*)dst)[i] = pk;
  }
}

// ---------------------------------------------------------------------------
// m97-structure GEMM: Y[m,n] = sum_k A[m,k]*B[n,k], all bf16 K-major.
// 128x128 tile, BK=32, global_load_lds width=16 staging (unpadded stride-32
// LDS — the wave-uniform-base + lane*16 contiguous layout), ds_read_b128
// fragments, 16 MFMA 16x16x32 per K-step.
// OUT_QKV: scatter bf16 into [b,h,s,dh] (z selects Q/K/V; Q scaled);
// else fp32 row-major [M][N] -> d_out.
// ---------------------------------------------------------------------------
template<bool OUT_QKV>
__global__ __launch_bounds__(256)
void gemm97(const u16* __restrict__ A,
            const u16* __restrict__ B0, const u16* __restrict__ B1,
            const u16* __restrict__ B2,
            u16* __restrict__ o0, u16* __restrict__ o1, u16* __restrict__ o2,
            float* __restrict__ oF)
{
  const int bx = blockIdx.x;
  const int by = blockIdx.y;
  const int bz = blockIdx.z;
  const u16* B = (bz == 0) ? B0 : ((bz == 1) ? B1 : B2);
  u16* oQ = (bz == 0) ? o0 : ((bz == 1) ? o1 : o2);

  __shared__ u16 As[128 * 32];
  __shared__ u16 Bs[128 * 32];

  const int tid  = threadIdx.x;
  const int w    = tid >> 6;
  const int lane = tid & 63;
  const int quad = lane >> 4;
  const int l15  = lane & 15;
  const int wm   = (w >> 1) * 64;
  const int wn   = (w & 1) * 64;

  // staging map: wave w stages rows w*32..w*32+31 of each tile;
  // lane i covers row (i>>2), 8-elem group (i&3) within a 16-row chunk.
  const int arb  = w * 32;
  const int srow = lane >> 2;
  const int scol = (lane & 3) * 8;
  const u16* ga = A + (size_t)(by * 128 + arb + srow) * 1024 + scol;
  const u16* gb = B + (size_t)(bx * 128 + arb + srow) * 1024 + scol;
  u16* la0 = &As[arb * 32];
  u16* la1 = &As[(arb + 16) * 32];
  u16* lb0 = &Bs[arb * 32];
  u16* lb1 = &Bs[(arb + 16) * 32];

  f32x4 acc[4][4];
  #pragma unroll
  for (int i = 0; i < 4; ++i)
    #pragma unroll
    for (int j = 0; j < 4; ++j)
      acc[i][j] = (f32x4){0.f, 0.f, 0.f, 0.f};

  for (int k0 = 0; k0 < 1024; k0 += 32) {
    gld16(ga + k0,               la0);
    gld16(ga + k0 + 16 * 1024,   la1);
    gld16(gb + k0,               lb0);
    gld16(gb + k0 + 16 * 1024,   lb1);
    __syncthreads();

    s16x8 af[4], bf[4];
    #pragma unroll
    for (int i = 0; i < 4; ++i)
      af[i] = *(const s16x8*)&As[(wm + i * 16 + l15) * 32 + quad * 8];
    #pragma unroll
    for (int i = 0; i < 4; ++i)
      bf[i] = *(const s16x8*)&Bs[(wn + i * 16 + l15) * 32 + quad * 8];
    #pragma unroll
    for (int mt = 0; mt < 4; ++mt)
      #pragma unroll
      for (int nt = 0; nt < 4; ++nt)
        acc[mt][nt] = __builtin_amdgcn_mfma_f32_16x16x32_bf16(
            af[mt], bf[nt], acc[mt][nt], 0, 0, 0);
    __syncthreads();
  }

  // epilogue: C/D layout col = lane&15, row = quad*4 + reg
  #pragma unroll
  for (int mt = 0; mt < 4; ++mt)
    #pragma unroll
    for (int nt = 0; nt < 4; ++nt)
      #pragma unroll
      for (int r = 0; r < 4; ++r) {
        const int row = by * 128 + wm + mt * 16 + quad * 4 + r;
        const int col = bx * 128 + wn + nt * 16 + l15;
        float v = acc[mt][nt][r];
        if (OUT_QKV) {
          if (bz == 0) v *= QSCALE;  // fold softmax scale+log2e into Q
          const int b = row >> 11, s = row & 2047, hh = col >> 6, d = col & 63;
          oQ[(size_t)(b * 16 + hh) * 131072 + s * 64 + d] = f2bf(v);
        } else {
          oF[(size_t)row * 1024 + col] = v;
        }
      }
}

// ---------------------------------------------------------------------------
// V transpose: [bh][2048][64] -> [bh][64][2048] (bf16)
// ---------------------------------------------------------------------------
__global__ __launch_bounds__(256)
void vtrans(const u16* __restrict__ Vb, u16* __restrict__ VT)
{
  const int st = blockIdx.x;   // 32 s-tiles of 64
  const int bh = blockIdx.y;   // 64
  __shared__ u16 T[64 * 72];
  const int tid = threadIdx.x;
  const size_t base = (size_t)bh * 131072;
  #pragma unroll
  for (int p = 0; p < 2; ++p) {
    const int idx = tid + p * 256;
    const int row = idx >> 3;
    const int col = (idx & 7) * 8;
    s16x8 v = *(const s16x8*)(Vb + base + (size_t)(st * 64 + row) * 64 + col);
    #pragma unroll
    for (int e = 0; e < 8; ++e) T[(col + e) * 72 + row] = v[e];
  }
  __syncthreads();
  #pragma unroll
  for (int p = 0; p < 2; ++p) {
    const int idx = tid + p * 256;
    const int drow = idx >> 3;
    const int scol = (idx & 7) * 8;
    *(s16x8*)(VT + base + (size_t)drow * 2048 + st * 64 + scol) =
        *(const s16x8*)&T[drow * 72 + scol];
  }
}

// ---------------------------------------------------------------------------
// Causal flash attention (unchanged from Round 2; 137 us, Occ 34%)
// ---------------------------------------------------------------------------
__global__ __launch_bounds__(256, 4)
void attn_kernel(const u16* __restrict__ Qg, const u16* __restrict__ Kg,
                 const u16* __restrict__ VTg, u16* __restrict__ out)
{
  const int pi = blockIdx.x;
  const int bh = blockIdx.y;
  const int b = bh >> 4, h = bh & 15;
  const int qa = 31 - pi;
  const int qb = pi;

  __shared__ u16 Qs[128 * 72];
  __shared__ u16 Ks[64 * 72];
  __shared__ u16 Vt[64 * 72];

  const int tid = threadIdx.x;
  const int w = tid >> 6, lane = tid & 63, quad = lane >> 4, l15 = lane & 15;
  const size_t base = (size_t)bh * 131072;

  {
    const int col = (tid & 7) * 8;
    #pragma unroll
    for (int p = 0; p < 4; ++p) {
      const int row = (tid >> 3) + p * 32;
      const int gq = (row < 64) ? (qa * 64 + row) : (qb * 64 + (row - 64));
      *(s16x8*)&Qs[row * 72 + col] =
          *(const s16x8*)(Qg + base + (size_t)gq * 64 + col);
    }
  }
  __syncthreads();

  const int myq  = (w < 2) ? qa : qb;
  const int wrow = (w & 1) * 32;
  const int qsb  = w * 32;

  s16x8 aq[2][2];
  #pragma unroll
  for (int mt = 0; mt < 2; ++mt)
    #pragma unroll
    for (int ks = 0; ks < 2; ++ks)
      aq[mt][ks] = *(const s16x8*)&Qs[(qsb + mt * 16 + l15) * 72 + ks * 32 + quad * 8];

  u16* Pw = &Qs[qsb * 72];

  s16x8 ones;
  #pragma unroll
  for (int e = 0; e < 8; ++e) ones[e] = (short)0x3F80;

  f32x4 O[2][4], liacc[2];
  float mi[2][4];
  #pragma unroll
  for (int mt = 0; mt < 2; ++mt) {
    #pragma unroll
    for (int dt = 0; dt < 4; ++dt) O[mt][dt] = (f32x4){0.f, 0.f, 0.f, 0.f};
    liacc[mt] = (f32x4){0.f, 0.f, 0.f, 0.f};
    #pragma unroll
    for (int r = 0; r < 4; ++r) mi[mt][r] = -1e30f;
  }

  const int jmax = qa + 1;
  for (int j = 0; j < jmax; ++j) {
    #pragma unroll
    for (int p = 0; p < 2; ++p) {
      const int idx = tid + p * 256;
      const int key = idx >> 3, col = (idx & 7) * 8;
      const int slot = (key & 3) * 16 + (key >> 2);
      *(s16x8*)&Ks[slot * 72 + col] =
          *(const s16x8*)(Kg + base + (size_t)(j * 64 + key) * 64 + col);
    }
    #pragma unroll
    for (int p = 0; p < 2; ++p) {
      const int idx = tid + p * 256;
      const int d = idx >> 3, col = (idx & 7) * 8;
      *(s16x8*)&Vt[d * 72 + col] =
          *(const s16x8*)(VTg + base + (size_t)d * 2048 + j * 64 + col);
    }
    __syncthreads();

    if (j <= myq) {
      f32x4 S[2][4];
      #pragma unroll
      for (int nt = 0; nt < 4; ++nt) {
        s16x8 b0 = *(const s16x8*)&Ks[(nt * 16 + l15) * 72 + quad * 8];
        s16x8 b1 = *(const s16x8*)&Ks[(nt * 16 + l15) * 72 + 32 + quad * 8];
        #pragma unroll
        for (int mt = 0; mt < 2; ++mt) {
          f32x4 z = (f32x4){0.f, 0.f, 0.f, 0.f};
          z = __builtin_amdgcn_mfma_f32_16x16x32_bf16(aq[mt][0], b0, z, 0, 0, 0);
          z = __builtin_amdgcn_mfma_f32_16x16x32_bf16(aq[mt][1], b1, z, 0, 0, 0);
          S[mt][nt] = z;
        }
      }
      if (j == myq) {
        #pragma unroll
        for (int mt = 0; mt < 2; ++mt)
          #pragma unroll
          for (int nt = 0; nt < 4; ++nt)
            #pragma unroll
            for (int r = 0; r < 4; ++r) {
              const int kg = 4 * l15 + nt;
              const int qg = wrow + mt * 16 + quad * 4 + r;
              if (kg > qg) S[mt][nt][r] = -1e30f;
            }
      }
      #pragma unroll
      for (int mt = 0; mt < 2; ++mt)
        #pragma unroll
        for (int r = 0; r < 4; ++r) {
          float rm = fmaxf(fmaxf(S[mt][0][r], S[mt][1][r]),
                           fmaxf(S[mt][2][r], S[mt][3][r]));
          #pragma unroll
          for (int off = 1; off < 16; off <<= 1)
            rm = fmaxf(rm, __shfl_xor(rm, off, 64));
          const float mold = mi[mt][r];
          const float mnew = fmaxf(mold, rm);
          const float alpha = __builtin_amdgcn_exp2f(mold - mnew);
          mi[mt][r] = mnew;
          const float p0 = __builtin_amdgcn_exp2f(S[mt][0][r] - mnew);
          const float p1 = __builtin_amdgcn_exp2f(S[mt][1][r] - mnew);
          const float p2 = __builtin_amdgcn_exp2f(S[mt][2][r] - mnew);
          const float p3 = __builtin_amdgcn_exp2f(S[mt][3][r] - mnew);
          liacc[mt][r] *= alpha;
          #pragma unroll
          for (int dt = 0; dt < 4; ++dt) O[mt][dt][r] *= alpha;
          s16x4 pk;
          pk[0] = (short)f2bf(p0); pk[1] = (short)f2bf(p1);
          pk[2] = (short)f2bf(p2); pk[3] = (short)f2bf(p3);
          *(s16x4*)&Pw[(mt * 16 + quad * 4 + r) * 72 + 4 * l15] = pk;
        }
      #pragma unroll
      for (int mt = 0; mt < 2; ++mt) {
        s16x8 a0 = *(const s16x8*)&Pw[(mt * 16 + l15) * 72 + quad * 8];
        s16x8 a1 = *(const s16x8*)&Pw[(mt * 16 + l15) * 72 + 32 + quad * 8];
        liacc[mt] = __builtin_amdgcn_mfma_f32_16x16x32_bf16(a0, ones, liacc[mt], 0, 0, 0);
        liacc[mt] = __builtin_amdgcn_mfma_f32_16x16x32_bf16(a1, ones, liacc[mt], 0, 0, 0);
        #pragma unroll
        for (int dt = 0; dt < 4; ++dt) {
          s16x8 b0 = *(const s16x8*)&Vt[(dt * 16 + l15) * 72 + quad * 8];
          s16x8 b1 = *(const s16x8*)&Vt[(dt * 16 + l15) * 72 + 32 + quad * 8];
          O[mt][dt] = __builtin_amdgcn_mfma_f32_16x16x32_bf16(a0, b0, O[mt][dt], 0, 0, 0);
          O[mt][dt] = __builtin_amdgcn_mfma_f32_16x16x32_bf16(a1, b1, O[mt][dt], 0, 0, 0);
        }
      }
    }
    __syncthreads();
  }

  #pragma unroll
  for (int mt = 0; mt < 2; ++mt)
    #pragma unroll
    for (int r = 0; r < 4; ++r) {
      const float inv = __builtin_amdgcn_rcpf(liacc[mt][r]);
      const int sq = myq * 64 + wrow + mt * 16 + quad * 4 + r;
      #pragma unroll
      for (int dt = 0; dt < 4; ++dt)
        out[(size_t)(b * 2048 + sq) * 1024 + h * 64 + dt * 16 + l15] =
            f2bf(O[mt][dt][r] * inv);
    }
}

extern "C" void kernel_launch(void* const* d_in, const int* in_sizes, int n_in,
                              void* d_out, int out_size, void* d_ws, size_t ws_size,
                              hipStream_t stream) {
  (void)in_sizes; (void)n_in; (void)out_size; (void)ws_size;
  const float* x  = (const float*)d_in[0];
  const float* Wq = (const float*)d_in[1];
  const float* Wk = (const float*)d_in[2];
  const float* Wv = (const float*)d_in[3];
  const float* Wo = (const float*)d_in[4];
  float* out = (float*)d_out;

  // workspace (u16 elems), 72 MB peak with aliasing:
  // [0)        xb  (x bf16)        -- dead after QKV gemm; reused as VT
  // [8388608)  Qb
  // [16777216) Kb
  // [25165824) Vb                  -- dead after vtrans; reused as AO
  // [33554432) Wqb,Wkb,Wvb,Wob (1048576 each)
  u16* W16 = (u16*)d_ws;
  u16* xb  = W16;
  u16* VT  = W16;                 // alias: x dead after QKV gemm
  u16* Qb  = W16 + 8388608;
  u16* Kb  = W16 + 16777216;
  u16* Vb  = W16 + 25165824;
  u16* AO  = Vb;                  // alias: V natural layout dead after vtrans
  u16* Wqb = W16 + 33554432;
  u16* Wkb = Wqb + 1048576;
  u16* Wvb = Wkb + 1048576;
  u16* Wob = Wvb + 1048576;

  dim3 blk(256);
  cvt_bf16<<<dim3(4096), blk, 0, stream>>>(x,  xb,  1048576);
  cvt_bf16<<<dim3(512),  blk, 0, stream>>>(Wq, Wqb, 131072);
  cvt_bf16<<<dim3(512),  blk, 0, stream>>>(Wk, Wkb, 131072);
  cvt_bf16<<<dim3(512),  blk, 0, stream>>>(Wv, Wvb, 131072);
  cvt_bf16<<<dim3(512),  blk, 0, stream>>>(Wo, Wob, 131072);

  gemm97<true ><<<dim3(8, 64, 3), blk, 0, stream>>>(
      xb, Wqb, Wkb, Wvb, Qb, Kb, Vb, nullptr);
  vtrans<<<dim3(32, 64), blk, 0, stream>>>(Vb, VT);
  attn_kernel<<<dim3(16, 64), blk, 0, stream>>>(Qb, Kb, VT, AO);
  gemm97<false><<<dim3(8, 64, 1), blk, 0, stream>>>(
      AO, Wob, Wob, Wob, nullptr, nullptr, nullptr, out);
}